// Round 1
// baseline (318.852 us; speedup 1.0000x reference)
//
#include <hip/hip_runtime.h>
#include <hip/hip_bf16.h>
#include <stdint.h>

// B=8192, T=U=1024, K=T+U=2048. GEMM: [8192,2048] x [2048, 4*1024]
#define NKT 32        // K tiles of BK=64
#define BK 64
#define BM 128        // rows per block
#define GCOLS 128     // 4 gates * 32 cols per block

typedef float f32x4 __attribute__((ext_vector_type(4)));
typedef __bf16 bf16x8 __attribute__((ext_vector_type(8)));

static __device__ __forceinline__ void gll16(const void* g, void* l) {
  __builtin_amdgcn_global_load_lds(
      (const __attribute__((address_space(1))) void*)g,
      (__attribute__((address_space(3))) void*)l, 16, 0, 0);
}

static __device__ __forceinline__ unsigned short f2bf(float f) {
  __hip_bfloat16 h = __float2bfloat16(f);
  union { __hip_bfloat16 h; unsigned short u; } v{h};
  return v.u;
}

// ---- pack A: concat(x,h) -> bf16, tiled [rb][kt][r=128][k=64], swizzled ----
// element (r,k) at byte  r*128 + ((k*2) ^ ((r&7)<<4))
__global__ void pack_a(const float* __restrict__ x, const float* __restrict__ h,
                       char* __restrict__ Ap) {
  int t   = blockIdx.x * 256 + threadIdx.x;  // one 16B chunk (8 k) per thread
  int row = t >> 8;          // 0..8191
  int cg  = t & 255;         // chunk within row (2048/8)
  int kt  = cg >> 3;         // 0..31
  int c   = cg & 7;          // chunk within K-tile
  int rb  = row >> 7;
  int r   = row & 127;
  int gk  = kt * 64 + c * 8;
  const float* src = (gk < 1024) ? (x + (size_t)row * 1024 + gk)
                                 : (h + (size_t)row * 1024 + (gk - 1024));
  float4 lo = *(const float4*)(src);
  float4 hi = *(const float4*)(src + 4);
  unsigned short o[8] = { f2bf(lo.x), f2bf(lo.y), f2bf(lo.z), f2bf(lo.w),
                          f2bf(hi.x), f2bf(hi.y), f2bf(hi.z), f2bf(hi.w) };
  size_t tile = ((size_t)rb * NKT + kt) * 16384;
  char* dst = Ap + tile + (size_t)r * 128 + ((c ^ (r & 7)) * 16);
  *(int4*)dst = *(const int4*)o;
}

// ---- pack W: transpose each W_g[k][col] -> bf16 Wt[gc][k], tiled [cb][kt][gc=128][k=64], swizzled
// element (gc,k) at byte  gc*128 + ((k*2) ^ ((gc&7)<<4)),  gc = g*32 + (col - cb*32)
__global__ void pack_w(const float* __restrict__ Wi, const float* __restrict__ Wf,
                       const float* __restrict__ Wg, const float* __restrict__ Wo,
                       char* __restrict__ Wp) {
  __shared__ float tile[64][33];   // +1 pad
  int kt = blockIdx.x, cb = blockIdx.y, g = blockIdx.z;
  const float* W = (g == 0) ? Wi : (g == 1) ? Wf : (g == 2) ? Wg : Wo;
  int t = threadIdx.x;
  // load 64 k-rows x 32 cols, coalesced
  {
    int k  = t >> 2;           // 0..63
    int co = (t & 3) * 8;      // 0,8,16,24
    const float* s = W + ((size_t)(kt * 64 + k)) * 1024 + cb * 32 + co;
    float4 lo = *(const float4*)s;
    float4 hi = *(const float4*)(s + 4);
    tile[k][co + 0] = lo.x; tile[k][co + 1] = lo.y; tile[k][co + 2] = lo.z; tile[k][co + 3] = lo.w;
    tile[k][co + 4] = hi.x; tile[k][co + 5] = hi.y; tile[k][co + 6] = hi.z; tile[k][co + 7] = hi.w;
  }
  __syncthreads();
  {
    int gcl = t >> 3;          // col within cb block, 0..31
    int cch = t & 7;           // k-chunk, 0..7
    int gc  = g * 32 + gcl;
    unsigned short o[8];
#pragma unroll
    for (int j = 0; j < 8; ++j) o[j] = f2bf(tile[cch * 8 + j][gcl]);
    size_t tb = ((size_t)cb * NKT + kt) * 16384;
    char* dst = Wp + tb + (size_t)gc * 128 + ((cch ^ (gc & 7)) * 16);
    *(int4*)dst = *(const int4*)o;
  }
}

// ---- fused GEMM (bf16 MFMA) + LSTM epilogue ----
// grid (32 cb, 64 rb), 256 threads = 4 waves; wave w: rows [w*32, w*32+32), all 128 gate-cols
__global__ __launch_bounds__(256, 2)
void lstm_gemm(const char* __restrict__ Ap, const char* __restrict__ Wp,
               const float* __restrict__ c_in,
               const float* __restrict__ b_i, const float* __restrict__ b_f,
               const float* __restrict__ b_g, const float* __restrict__ b_o,
               float* __restrict__ out) {
  __shared__ __align__(128) char smem[32768];
  char* sA = smem;            // 16 KB: [r=128][k=64] bf16 swizzled
  char* sB = smem + 16384;    // 16 KB: [gc=128][k=64] bf16 swizzled

  int cb = blockIdx.x, rb = blockIdx.y;
  int tid = threadIdx.x;
  int w = tid >> 6, lane = tid & 63;
  int l15 = lane & 15, lq = lane >> 4;

  f32x4 acc[2][8] = {};

  const char* aBase = Ap + ((size_t)rb * NKT) * 16384;
  const char* bBase = Wp + ((size_t)cb * NKT) * 16384;

  int rA0 = w * 32 + l15;
  int rA1 = rA0 + 16;
  int aSwz0 = (rA0 & 7) << 4, aSwz1 = (rA1 & 7) << 4;

  for (int kt = 0; kt < NKT; ++kt) {
    const char* at = aBase + (size_t)kt * 16384;
    const char* bt = bBase + (size_t)kt * 16384;
#pragma unroll
    for (int i = 0; i < 4; ++i) {
      int ldso = (i * 4 + w) * 1024;
      int off  = ldso + lane * 16;
      gll16(at + off, sA + ldso);
      gll16(bt + off, sB + ldso);
    }
    __syncthreads();
#pragma unroll
    for (int ks = 0; ks < 2; ++ks) {
      int kterm = ks * 64 + lq * 16;
      bf16x8 a0 = *(const bf16x8*)(sA + rA0 * 128 + (kterm ^ aSwz0));
      bf16x8 a1 = *(const bf16x8*)(sA + rA1 * 128 + (kterm ^ aSwz1));
#pragma unroll
      for (int n = 0; n < 8; ++n) {
        int gc = n * 16 + l15;
        bf16x8 b = *(const bf16x8*)(sB + gc * 128 + (kterm ^ ((gc & 7) << 4)));
        acc[0][n] = __builtin_amdgcn_mfma_f32_16x16x32_bf16(a0, b, acc[0][n], 0, 0, 0);
        acc[1][n] = __builtin_amdgcn_mfma_f32_16x16x32_bf16(a1, b, acc[1][n], 0, 0, 0);
      }
    }
    __syncthreads();
  }

  // epilogue: n-frags {0,1}=i, {2,3}=f, {4,5}=g, {6,7}=o
  const size_t HN = (size_t)8192 * 1024;
#pragma unroll
  for (int ci = 0; ci < 2; ++ci) {
    int col = cb * 32 + ci * 16 + l15;
    float bi = b_i[col], bf = b_f[col], bg = b_g[col], bo = b_o[col];
#pragma unroll
    for (int m = 0; m < 2; ++m) {
      f32x4 zi = acc[m][0 + ci], zf = acc[m][2 + ci];
      f32x4 zg = acc[m][4 + ci], zo = acc[m][6 + ci];
      int row0 = rb * 128 + w * 32 + m * 16 + lq * 4;
#pragma unroll
      for (int r = 0; r < 4; ++r) {
        int row = row0 + r;
        float xi = zi[r] + bi, xf = zf[r] + bf, xg = zg[r] + bg, xo = zo[r] + bo;
        float iv = 1.f / (1.f + __expf(-xi));
        float fv = 1.f / (1.f + __expf(-xf));
        float gv = 1.f - 2.f / (__expf(2.f * xg) + 1.f);
        float ov = 1.f / (1.f + __expf(-xo));
        float cv = c_in[(size_t)row * 1024 + col];
        float cn = fv * cv + iv * gv;
        float tc = 1.f - 2.f / (__expf(2.f * cn) + 1.f);
        out[(size_t)row * 1024 + col]      = ov * tc;  // h_new
        out[HN + (size_t)row * 1024 + col] = cn;       // c_new
      }
    }
  }
}

extern "C" void kernel_launch(void* const* d_in, const int* in_sizes, int n_in,
                              void* d_out, int out_size, void* d_ws, size_t ws_size,
                              hipStream_t stream) {
  const float* x  = (const float*)d_in[0];
  const float* h  = (const float*)d_in[1];
  const float* c  = (const float*)d_in[2];
  const float* Wi = (const float*)d_in[3];
  const float* Wf = (const float*)d_in[4];
  const float* Wg = (const float*)d_in[5];
  const float* Wo = (const float*)d_in[6];
  const float* bi = (const float*)d_in[7];
  const float* bf = (const float*)d_in[8];
  const float* bg = (const float*)d_in[9];
  const float* bo = (const float*)d_in[10];

  char* Ap = (char*)d_ws;                               // 8192*2048*2 = 32 MB
  char* Wp = Ap + (size_t)8192 * 2048 * 2;              // 2048*4096*2 = 16 MB
  float* out = (float*)d_out;

  hipLaunchKernelGGL(pack_a, dim3(8192), dim3(256), 0, stream, x, h, Ap);
  hipLaunchKernelGGL(pack_w, dim3(32, 32, 4), dim3(256), 0, stream, Wi, Wf, Wg, Wo, Wp);
  hipLaunchKernelGGL(lstm_gemm, dim3(32, 64), dim3(256), 0, stream,
                     Ap, Wp, c, bi, bf, bg, bo, out);
}

// Round 2
// 313.312 us; speedup vs baseline: 1.0177x; 1.0177x over previous
//
#include <hip/hip_runtime.h>
#include <hip/hip_bf16.h>
#include <stdint.h>

// B=8192, T=U=1024, K=2048. GEMM: [8192,2048] x [2048,4096 packed gate cols]
// Packed col: pc = (c>>4)*64 + g*16 + (c&15)  (c = real col, g = gate)
// Pack tile = 16 KB: [256 rows][BK=32 k] bf16, chunk(r,kq) = r*4 + (kq ^ ((r>>1)&3))
// (kq = 16B chunk of 8 bf16 along k). 2-way bank aliasing on ds_read_b128 = free.

typedef float f32x4 __attribute__((ext_vector_type(4)));
typedef __bf16 bf16x8 __attribute__((ext_vector_type(8)));

static __device__ __forceinline__ void gll16(const void* g, void* l) {
  __builtin_amdgcn_global_load_lds(
      (const __attribute__((address_space(1))) void*)g,
      (__attribute__((address_space(3))) void*)l, 16, 0, 0);
}

static __device__ __forceinline__ unsigned short f2bf(float f) {
  union { __hip_bfloat16 h; unsigned short u; } v{__float2bfloat16(f)};
  return v.u;
}

// ---- pack A: concat(x,h) -> bf16 tiles [rbB 0..31][kt 0..63][chunk 0..1023]
__global__ void pack_a(const float* __restrict__ x, const float* __restrict__ h,
                       char* __restrict__ Ap) {
  int row = blockIdx.x;            // 0..8191
  int c8  = threadIdx.x;           // 0..255  (k-chunk of 8)
  int kt  = c8 >> 2, kq = c8 & 3;
  int gk  = c8 * 8;
  const float* src = (gk < 1024) ? (x + (size_t)row * 1024 + gk)
                                 : (h + (size_t)row * 1024 + (gk - 1024));
  float4 lo = *(const float4*)src;
  float4 hi = *(const float4*)(src + 4);
  __attribute__((aligned(16))) unsigned short o[8] = {
      f2bf(lo.x), f2bf(lo.y), f2bf(lo.z), f2bf(lo.w),
      f2bf(hi.x), f2bf(hi.y), f2bf(hi.z), f2bf(hi.w) };
  int r = row & 255;
  int chunk = r * 4 + (kq ^ ((r >> 1) & 3));
  char* dst = Ap + ((size_t)((row >> 8) * 64 + kt)) * 16384 + chunk * 16;
  *(int4*)dst = *(const int4*)o;
}

// ---- pack W: [cbo 0..15][kt 0..63][chunk], gc = ((c>>4)&3)*64 + g*16 + (c&15)
__global__ void pack_w(const float* __restrict__ Wi, const float* __restrict__ Wf,
                       const float* __restrict__ Wg, const float* __restrict__ Wo,
                       char* __restrict__ Wp) {
  __shared__ float tile[32][65];
  int kt = blockIdx.x;       // 0..63  (k in [kt*32, +32))
  int cbo = blockIdx.y;      // 0..15  (c in [cbo*64, +64))
  int g = blockIdx.z;        // 0..3
  const float* W = (g == 0) ? Wi : (g == 1) ? Wf : (g == 2) ? Wg : Wo;
  int t = threadIdx.x;
  {
    int k  = t >> 3;          // 0..31
    int c8 = (t & 7) * 8;
    const float* s = W + (size_t)(kt * 32 + k) * 1024 + cbo * 64 + c8;
    float4 lo = *(const float4*)s;
    float4 hi = *(const float4*)(s + 4);
    tile[k][c8 + 0] = lo.x; tile[k][c8 + 1] = lo.y; tile[k][c8 + 2] = lo.z; tile[k][c8 + 3] = lo.w;
    tile[k][c8 + 4] = hi.x; tile[k][c8 + 5] = hi.y; tile[k][c8 + 6] = hi.z; tile[k][c8 + 7] = hi.w;
  }
  __syncthreads();
  {
    int cl = t >> 2;          // 0..63
    int kq = t & 3;
    __attribute__((aligned(16))) unsigned short o[8];
#pragma unroll
    for (int j = 0; j < 8; ++j) o[j] = f2bf(tile[kq * 8 + j][cl]);
    int gc = ((cl >> 4) & 3) * 64 + g * 16 + (cl & 15);
    int chunk = gc * 4 + (kq ^ ((gc >> 1) & 3));
    char* dst = Wp + ((size_t)(cbo * 64 + kt)) * 16384 + chunk * 16;
    *(int4*)dst = *(const int4*)o;
  }
}

// ---- 256x256 GEMM, 8 waves (2M x 4N), BK=32, ring of 4 LDS buffers,
// counted vmcnt(8), raw barriers, setprio around MFMA, fused LSTM epilogue.
__global__ __launch_bounds__(512, 2)
void lstm_gemm(const char* __restrict__ Ap, const char* __restrict__ Wp,
               const float* __restrict__ c_in,
               const float* __restrict__ b_i, const float* __restrict__ b_f,
               const float* __restrict__ b_g, const float* __restrict__ b_o,
               float* __restrict__ out) {
  __shared__ __align__(128) char smem[131072];  // 4 bufs x (A 16K + B 16K)

  int tid = threadIdx.x;
  int w = tid >> 6, lane = tid & 63, l15 = lane & 15, lq = lane >> 4;
  int wm = w >> 2, wc = w & 3;

  // XCD-aware swizzle: 512 blocks, 8 XCDs, chunk = 4 rb x 16 cb
  int bid = blockIdx.x;
  int wg = (bid & 7) * 64 + (bid >> 3);
  int rbB = wg >> 4, cb = wg & 15;

  const char* aT = Ap + (size_t)rbB * (64 * 16384);
  const char* bT = Wp + (size_t)cb * (64 * 16384);

  f32x4 acc[8][4] = {};

  int aOff[8], bOff[4];
#pragma unroll
  for (int m = 0; m < 8; ++m) {
    int r = wm * 128 + m * 16 + l15;
    aOff[m] = r * 64 + ((lq ^ ((r >> 1) & 3)) << 4);
  }
#pragma unroll
  for (int n = 0; n < 4; ++n) {
    int gc = wc * 64 + n * 16 + l15;
    bOff[n] = gc * 64 + ((lq ^ ((gc >> 1) & 3)) << 4);
  }

  auto stgA = [&](int kt) {
    const char* s = aT + (size_t)kt * 16384 + tid * 16;
    char* d = smem + (kt & 3) * 32768 + tid * 16;
    gll16(s, d); gll16(s + 8192, d + 8192);
  };
  auto stgB = [&](int kt) {
    const char* s = bT + (size_t)kt * 16384 + tid * 16;
    char* d = smem + (kt & 3) * 32768 + 16384 + tid * 16;
    gll16(s, d); gll16(s + 8192, d + 8192);
  };

  // prologue: stage Kt0,1,2 (12 loads); wait till Kt0 arrived (8 left)
  stgA(0); stgB(0); stgA(1); stgB(1); stgA(2); stgB(2);
  asm volatile("s_waitcnt vmcnt(8)" ::: "memory");
  __builtin_amdgcn_s_barrier();

  for (int j = 0; j < 64; ++j) {
    const char* sA = smem + (j & 3) * 32768;
    const char* sB = sA + 16384;
    int js = (j + 3) & 63;  // wrapped tail staging is harmless (buf already consumed)

    bf16x8 aF[4], bF[4], aG[4];
    // phase A: 8 ds_reads + stage A(j+3) + barrier + 16 MFMA
#pragma unroll
    for (int m = 0; m < 4; ++m) aF[m] = *(const bf16x8*)(sA + aOff[m]);
#pragma unroll
    for (int n = 0; n < 4; ++n) bF[n] = *(const bf16x8*)(sB + bOff[n]);
    stgA(js);
    __builtin_amdgcn_s_barrier();
    __builtin_amdgcn_s_setprio(1);
#pragma unroll
    for (int m = 0; m < 4; ++m)
#pragma unroll
      for (int n = 0; n < 4; ++n)
        acc[m][n] = __builtin_amdgcn_mfma_f32_16x16x32_bf16(aF[m], bF[n], acc[m][n], 0, 0, 0);
    __builtin_amdgcn_s_setprio(0);
    __builtin_amdgcn_s_barrier();

    // phase B: 4 ds_reads (reuse bF) + stage B(j+3) + barrier + 16 MFMA
#pragma unroll
    for (int m = 0; m < 4; ++m) aG[m] = *(const bf16x8*)(sA + aOff[4 + m]);
    stgB(js);
    __builtin_amdgcn_s_barrier();
    __builtin_amdgcn_s_setprio(1);
#pragma unroll
    for (int m = 0; m < 4; ++m)
#pragma unroll
      for (int n = 0; n < 4; ++n)
        acc[4 + m][n] = __builtin_amdgcn_mfma_f32_16x16x32_bf16(aG[m], bF[n], acc[4 + m][n], 0, 0, 0);
    __builtin_amdgcn_s_setprio(0);
    // counted wait: of {j+1,j+2,j+3} (12 loads) leave 8 -> Kt j+1 fully in LDS
    asm volatile("s_waitcnt vmcnt(8)" ::: "memory");
    __builtin_amdgcn_s_barrier();
  }

  // ---- fused LSTM epilogue: nf 0..3 = gates i,f,g,o at the same column ----
  int col = (cb * 4 + wc) * 16 + l15;
  float Bi = b_i[col], Bf = b_f[col], Bg = b_g[col], Bo = b_o[col];
  const size_t HN = (size_t)8192 * 1024;
#pragma unroll
  for (int mf = 0; mf < 8; ++mf) {
    int row0 = rbB * 256 + wm * 128 + mf * 16 + lq * 4;
#pragma unroll
    for (int r = 0; r < 4; ++r) {
      int row = row0 + r;
      float xi = acc[mf][0][r] + Bi, xf = acc[mf][1][r] + Bf;
      float xg = acc[mf][2][r] + Bg, xo = acc[mf][3][r] + Bo;
      float iv = 1.f / (1.f + __expf(-xi));
      float fv = 1.f / (1.f + __expf(-xf));
      float gv = 1.f - 2.f / (__expf(2.f * xg) + 1.f);
      float ov = 1.f / (1.f + __expf(-xo));
      float cv = c_in[(size_t)row * 1024 + col];
      float cn = fv * cv + iv * gv;
      float tc = 1.f - 2.f / (__expf(2.f * cn) + 1.f);
      out[(size_t)row * 1024 + col]      = ov * tc;  // h_new
      out[HN + (size_t)row * 1024 + col] = cn;       // c_new
    }
  }
}

extern "C" void kernel_launch(void* const* d_in, const int* in_sizes, int n_in,
                              void* d_out, int out_size, void* d_ws, size_t ws_size,
                              hipStream_t stream) {
  const float* x  = (const float*)d_in[0];
  const float* h  = (const float*)d_in[1];
  const float* c  = (const float*)d_in[2];
  const float* Wi = (const float*)d_in[3];
  const float* Wf = (const float*)d_in[4];
  const float* Wg = (const float*)d_in[5];
  const float* Wo = (const float*)d_in[6];
  const float* bi = (const float*)d_in[7];
  const float* bf = (const float*)d_in[8];
  const float* bg = (const float*)d_in[9];
  const float* bo = (const float*)d_in[10];

  char* Ap = (char*)d_ws;                               // 32 MB
  char* Wp = Ap + (size_t)8192 * 2048 * 2;              // 16 MB
  float* out = (float*)d_out;

  hipLaunchKernelGGL(pack_a, dim3(8192), dim3(256), 0, stream, x, h, Ap);
  hipLaunchKernelGGL(pack_w, dim3(64, 16, 4), dim3(256), 0, stream, Wi, Wf, Wg, Wo, Wp);
  hipLaunchKernelGGL(lstm_gemm, dim3(512), dim3(512), 0, stream,
                     Ap, Wp, c, bi, bf, bg, bo, out);
}

// Round 4
// 310.281 us; speedup vs baseline: 1.0276x; 1.0098x over previous
//
#include <hip/hip_runtime.h>
#include <hip/hip_bf16.h>
#include <stdint.h>

// B=8192, T=U=1024, K=2048. GEMM: [8192,2048] x [2048,4096 packed gate cols]
// Packed col: pc = (c>>4)*64 + g*16 + (c&15)
// Pack tile = 16 KB: [256 rows][BK=32 k] bf16, chunk(r,kq) = r*4 + (kq ^ ((r>>1)&3))

typedef float f32x4 __attribute__((ext_vector_type(4)));
typedef __bf16 bf16x8 __attribute__((ext_vector_type(8)));

static __device__ __forceinline__ void gll16(const void* g, void* l) {
  __builtin_amdgcn_global_load_lds(
      (const __attribute__((address_space(1))) void*)g,
      (__attribute__((address_space(3))) void*)l, 16, 0, 0);
}

// inline-asm LDS read on a 32-bit LDS byte offset (guaranteed DS-encoded,
// invisible to the waitcnt pass -> our counted vmcnt protocol survives)
static __device__ __forceinline__ bf16x8 ldsr(unsigned a) {
  bf16x8 r;
  asm volatile("ds_read_b128 %0, %1" : "=v"(r) : "v"(a));
  return r;
}

static __device__ __forceinline__ unsigned short f2bf(float f) {
  union { __hip_bfloat16 h; unsigned short u; } v{__float2bfloat16(f)};
  return v.u;
}

// ---- pack A: concat(x,h) -> bf16 tiles [rbB 0..31][kt 0..63][chunk 0..1023]
__global__ void pack_a(const float* __restrict__ x, const float* __restrict__ h,
                       char* __restrict__ Ap) {
  int row = blockIdx.x;
  int c8  = threadIdx.x;
  int kt  = c8 >> 2, kq = c8 & 3;
  int gk  = c8 * 8;
  const float* src = (gk < 1024) ? (x + (size_t)row * 1024 + gk)
                                 : (h + (size_t)row * 1024 + (gk - 1024));
  float4 lo = *(const float4*)src;
  float4 hi = *(const float4*)(src + 4);
  __attribute__((aligned(16))) unsigned short o[8] = {
      f2bf(lo.x), f2bf(lo.y), f2bf(lo.z), f2bf(lo.w),
      f2bf(hi.x), f2bf(hi.y), f2bf(hi.z), f2bf(hi.w) };
  int r = row & 255;
  int chunk = r * 4 + (kq ^ ((r >> 1) & 3));
  char* dst = Ap + ((size_t)((row >> 8) * 64 + kt)) * 16384 + chunk * 16;
  *(int4*)dst = *(const int4*)o;
}

// ---- pack W: [cbo 0..15][kt 0..63][chunk], gc = ((c>>4)&3)*64 + g*16 + (c&15)
__global__ void pack_w(const float* __restrict__ Wi, const float* __restrict__ Wf,
                       const float* __restrict__ Wg, const float* __restrict__ Wo,
                       char* __restrict__ Wp) {
  __shared__ float tile[32][65];
  int kt = blockIdx.x;
  int cbo = blockIdx.y;
  int g = blockIdx.z;
  const float* W = (g == 0) ? Wi : (g == 1) ? Wf : (g == 2) ? Wg : Wo;
  int t = threadIdx.x;
  {
    int k  = t >> 3;
    int c8 = (t & 7) * 8;
    const float* s = W + (size_t)(kt * 32 + k) * 1024 + cbo * 64 + c8;
    float4 lo = *(const float4*)s;
    float4 hi = *(const float4*)(s + 4);
    tile[k][c8 + 0] = lo.x; tile[k][c8 + 1] = lo.y; tile[k][c8 + 2] = lo.z; tile[k][c8 + 3] = lo.w;
    tile[k][c8 + 4] = hi.x; tile[k][c8 + 5] = hi.y; tile[k][c8 + 6] = hi.z; tile[k][c8 + 7] = hi.w;
  }
  __syncthreads();
  {
    int cl = t >> 2;
    int kq = t & 3;
    __attribute__((aligned(16))) unsigned short o[8];
#pragma unroll
    for (int j = 0; j < 8; ++j) o[j] = f2bf(tile[kq * 8 + j][cl]);
    int gc = ((cl >> 4) & 3) * 64 + g * 16 + (cl & 15);
    int chunk = gc * 4 + (kq ^ ((gc >> 1) & 3));
    char* dst = Wp + ((size_t)(cbo * 64 + kt)) * 16384 + chunk * 16;
    *(int4*)dst = *(const int4*)o;
  }
}

// ---- 256x256 GEMM, 8 waves (2M x 4N), BK=32, ring-4 LDS, counted vmcnt,
// asm ds_read_b128 + explicit lgkmcnt(0) + sched_barrier(0), fused epilogue.
__global__ __launch_bounds__(512, 2)
void lstm_gemm(const char* __restrict__ Ap, const char* __restrict__ Wp,
               const float* __restrict__ c_in,
               const float* __restrict__ b_i, const float* __restrict__ b_f,
               const float* __restrict__ b_g, const float* __restrict__ b_o,
               float* __restrict__ out) {
  __shared__ __align__(128) char smem[131072];  // 4 bufs x (A 16K + B 16K)

  int tid = threadIdx.x;
  int w = tid >> 6, lane = tid & 63, l15 = lane & 15, lq = lane >> 4;
  int wm = w >> 2, wc = w & 3;

  int bid = blockIdx.x;
  int wg = (bid & 7) * 64 + (bid >> 3);   // 512 % 8 == 0 -> bijective
  int rbB = wg >> 4, cb = wg & 15;

  const char* aT = Ap + (size_t)rbB * (64 * 16384);
  const char* bT = Wp + (size_t)cb * (64 * 16384);

  f32x4 acc[8][4] = {};

  unsigned ldsBase = (unsigned)(size_t)(__attribute__((address_space(3))) char*)smem;

  unsigned aOff[8], bOff[4];
#pragma unroll
  for (int m = 0; m < 8; ++m) {
    int r = wm * 128 + m * 16 + l15;
    aOff[m] = (unsigned)(r * 64 + ((lq ^ ((r >> 1) & 3)) << 4));
  }
#pragma unroll
  for (int n = 0; n < 4; ++n) {
    int gc = wc * 64 + n * 16 + l15;
    bOff[n] = (unsigned)(16384 + gc * 64 + ((lq ^ ((gc >> 1) & 3)) << 4));
  }

  auto stgA = [&](int kt) {
    const char* s = aT + (size_t)kt * 16384 + tid * 16;
    char* d = smem + (kt & 3) * 32768 + tid * 16;
    gll16(s, d); gll16(s + 8192, d + 8192);
  };
  auto stgB = [&](int kt) {
    const char* s = bT + (size_t)kt * 16384 + tid * 16;
    char* d = smem + (kt & 3) * 32768 + 16384 + tid * 16;
    gll16(s, d); gll16(s + 8192, d + 8192);
  };

  // prologue: stage Kt0,1,2 (12 loads); wait till Kt0 arrived (8 left)
  stgA(0); stgB(0); stgA(1); stgB(1); stgA(2); stgB(2);
  asm volatile("s_waitcnt vmcnt(8)" ::: "memory");
  __builtin_amdgcn_s_barrier();

  for (int j = 0; j < 64; ++j) {
    unsigned sb = ldsBase + (unsigned)((j & 3) * 32768);
    int js = (j + 3) & 63;  // wrapped tail re-stage is harmless (drained below)

    // ---- phase A: 8 asm ds_reads + stage A(j+3) + bar + lgkm0 + 16 MFMA ----
    bf16x8 aF[4], bF[4], aG[4];
#pragma unroll
    for (int m = 0; m < 4; ++m) aF[m] = ldsr(sb + aOff[m]);
#pragma unroll
    for (int n = 0; n < 4; ++n) bF[n] = ldsr(sb + bOff[n]);
    stgA(js);
    __builtin_amdgcn_s_barrier();
    asm volatile("s_waitcnt lgkmcnt(0)");
    __builtin_amdgcn_sched_barrier(0);
    __builtin_amdgcn_s_setprio(1);
#pragma unroll
    for (int m = 0; m < 4; ++m)
#pragma unroll
      for (int n = 0; n < 4; ++n)
        acc[m][n] = __builtin_amdgcn_mfma_f32_16x16x32_bf16(aF[m], bF[n], acc[m][n], 0, 0, 0);
    __builtin_amdgcn_s_setprio(0);
    __builtin_amdgcn_s_barrier();

    // ---- phase B: 4 asm ds_reads (reuse bF) + stage B(j+3) + bar + 16 MFMA --
#pragma unroll
    for (int m = 0; m < 4; ++m) aG[m] = ldsr(sb + aOff[4 + m]);
    stgB(js);
    __builtin_amdgcn_s_barrier();
    asm volatile("s_waitcnt lgkmcnt(0)");
    __builtin_amdgcn_sched_barrier(0);
    __builtin_amdgcn_s_setprio(1);
#pragma unroll
    for (int m = 0; m < 4; ++m)
#pragma unroll
      for (int n = 0; n < 4; ++n)
        acc[4 + m][n] = __builtin_amdgcn_mfma_f32_16x16x32_bf16(aG[m], bF[n], acc[4 + m][n], 0, 0, 0);
    __builtin_amdgcn_s_setprio(0);
    // counted wait: leave 8 outstanding -> Kt j+1 fully in LDS, j+2/j+3 in flight
    asm volatile("s_waitcnt vmcnt(8)" ::: "memory");
    __builtin_amdgcn_s_barrier();
  }
  // drain tail stages before epilogue / endpgm (LDS-DMA must not outlive block)
  asm volatile("s_waitcnt vmcnt(0)" ::: "memory");

  // ---- fused LSTM epilogue: nf 0..3 = gates i,f,g,o at the same column ----
  int col = (cb * 4 + wc) * 16 + l15;
  float Bi = b_i[col], Bf = b_f[col], Bg = b_g[col], Bo = b_o[col];
  const size_t HN = (size_t)8192 * 1024;
#pragma unroll
  for (int mf = 0; mf < 8; ++mf) {
    int row0 = rbB * 256 + wm * 128 + mf * 16 + lq * 4;
#pragma unroll
    for (int r = 0; r < 4; ++r) {
      int row = row0 + r;
      float xi = acc[mf][0][r] + Bi, xf = acc[mf][1][r] + Bf;
      float xg = acc[mf][2][r] + Bg, xo = acc[mf][3][r] + Bo;
      float iv = 1.f / (1.f + __expf(-xi));
      float fv = 1.f / (1.f + __expf(-xf));
      float gv = 1.f - 2.f / (__expf(2.f * xg) + 1.f);
      float ov = 1.f / (1.f + __expf(-xo));
      float cv = c_in[(size_t)row * 1024 + col];
      float cn = fv * cv + iv * gv;
      float tc = 1.f - 2.f / (__expf(2.f * cn) + 1.f);
      out[(size_t)row * 1024 + col]      = ov * tc;  // h_new
      out[HN + (size_t)row * 1024 + col] = cn;       // c_new
    }
  }
}

extern "C" void kernel_launch(void* const* d_in, const int* in_sizes, int n_in,
                              void* d_out, int out_size, void* d_ws, size_t ws_size,
                              hipStream_t stream) {
  const float* x  = (const float*)d_in[0];
  const float* h  = (const float*)d_in[1];
  const float* c  = (const float*)d_in[2];
  const float* Wi = (const float*)d_in[3];
  const float* Wf = (const float*)d_in[4];
  const float* Wg = (const float*)d_in[5];
  const float* Wo = (const float*)d_in[6];
  const float* bi = (const float*)d_in[7];
  const float* bf = (const float*)d_in[8];
  const float* bg = (const float*)d_in[9];
  const float* bo = (const float*)d_in[10];

  char* Ap = (char*)d_ws;                               // 32 MB
  char* Wp = Ap + (size_t)8192 * 2048 * 2;              // 16 MB
  float* out = (float*)d_out;

  hipLaunchKernelGGL(pack_a, dim3(8192), dim3(256), 0, stream, x, h, Ap);
  hipLaunchKernelGGL(pack_w, dim3(64, 16, 4), dim3(256), 0, stream, Wi, Wf, Wg, Wo, Wp);
  hipLaunchKernelGGL(lstm_gemm, dim3(512), dim3(512), 0, stream,
                     Ap, Wp, c, bi, bf, bg, bo, out);
}